// Round 5
// baseline (5028.985 us; speedup 1.0000x reference)
//
#include <hip/hip_runtime.h>
#include <hip/hip_bf16.h>

// LSTM: B=64, T=512, IN=512, H=1024, gates i,f,g,o.
// Persistent kernel, 128 blocks x 256 threads.
// R5: grid sync via per-block TAG ARRAY instead of atomic tree. Writer:
// drain (via __syncthreads) -> one store-release tag[bid]=t+1 (no RMW, no
// contention). Reader: wave 0 polls all 128 tags in one vector round
// (2 sc1 loads/lane + __all). Removes ~2 serialized LLC RTs per step.
// Else unchanged from R4: 65 rotating h buffers, sc1 h stores, cached
// global_load_lds h DMA, acquire fence every 32 steps, W_hh in regs,
// W_ih bf16 in LDS, XOR-swizzled conflict-free layouts.

#define Bx 64
#define Tx 512
#define INx 512
#define Hx 1024
#define NBLK 128
#define UNITS 8
#define NBUF 65            // rotating h buffers

typedef __attribute__((ext_vector_type(8))) short short8;
typedef __attribute__((ext_vector_type(4))) float floatx4;

// normal cached direct-to-LDS copy (L2-allocating)
#define ASYNC_CP(gp, lp)                                                      \
  __builtin_amdgcn_global_load_lds(                                           \
      (const __attribute__((address_space(1))) void*)(gp),                    \
      (__attribute__((address_space(3))) void*)(lp), 16, 0, 0)

__device__ __forceinline__ unsigned short f2bf(float f) {
  unsigned u = __float_as_uint(f);
  u += 0x7FFFu + ((u >> 16) & 1u);   // round-to-nearest-even
  return (unsigned short)(u >> 16);
}
__device__ __forceinline__ float sigm(float x) { return 1.0f / (1.0f + __expf(-x)); }
__device__ __forceinline__ float tanh_(float x) { return 1.0f - 2.0f / (1.0f + __expf(2.0f * x)); }

// Convert input [B][T][IN] fp32 -> xT [T][B][IN] bf16
__global__ void convert_x_kernel(const float* __restrict__ in, unsigned short* __restrict__ xT) {
  int idx = blockIdx.x * 256 + threadIdx.x;
  int lin = idx * 8;
  int t = lin >> 15;
  int rem = lin & 32767;
  int b = rem >> 9;
  int k = rem & 511;
  const float* src = in + ((((b << 9) + t) << 9) + k);
  float4 lo = *(const float4*)src;
  float4 hi = *(const float4*)(src + 4);
  short8 o;
  o[0] = (short)f2bf(lo.x); o[1] = (short)f2bf(lo.y);
  o[2] = (short)f2bf(lo.z); o[3] = (short)f2bf(lo.w);
  o[4] = (short)f2bf(hi.x); o[5] = (short)f2bf(hi.y);
  o[6] = (short)f2bf(hi.z); o[7] = (short)f2bf(hi.w);
  *(short8*)(xT + lin) = o;
}

__global__ __launch_bounds__(256, 1) void lstm_persistent(
    const float* __restrict__ W_ih, const float* __restrict__ W_hh,
    const float* __restrict__ b_ih, const float* __restrict__ b_hh,
    const unsigned short* __restrict__ xT,   // [T][B][IN] bf16
    unsigned short* __restrict__ hbuf,       // [NBUF][B][H] bf16 (buf 0 zeroed)
    unsigned int* __restrict__ tags,         // 128 uints (zeroed)
    float* __restrict__ out)                 // [B][H] fp32
{
  // h: 64 rows x 1024 shorts, 16B-chunk c of row m at c^(m&7)   (128 KiB)
  // wih: 32 rows x 512 shorts, chunk c of row n at c^(n&7)      (32 KiB)
  __shared__ short hsh[Bx * Hx];
  __shared__ short wsh[32 * INx];

  const int tid = threadIdx.x;
  const int wv = tid >> 6;
  const int lane = tid & 63;
  const int quad = lane >> 4;
  const int col = lane & 15;
  const int swz = col & 7;
  const int bid = blockIdx.x;
  const int j0 = bid * UNITS;
  const int m0 = wv * 16;            // batch-row base for this wave

  // ---- stage W_ih slice (fp32 -> bf16, swizzled) into LDS ----
  for (int idx = tid; idx < 32 * INx; idx += 256) {
    int n = idx >> 9;
    int k = idx & (INx - 1);
    int row = ((n >> 3) * Hx) + j0 + (n & 7);
    int c = k >> 3;
    wsh[n * INx + (((c ^ (n & 7)) << 3) | (k & 7))] = f2bf(W_ih[row * INx + k]);
  }

  // ---- preload W_hh B-fragments into registers ----
  short8 wf[32][2];
#pragma unroll
  for (int kt = 0; kt < 32; ++kt) {
#pragma unroll
    for (int nt = 0; nt < 2; ++nt) {
      int n = nt * 16 + col;
      int row = ((n >> 3) * Hx) + j0 + (n & 7);
      const float* p = W_hh + row * Hx + kt * 32 + quad * 8;
      short8 w;
#pragma unroll
      for (int j = 0; j < 8; ++j) w[j] = (short)f2bf(p[j]);
      wf[kt][nt] = w;
    }
  }

  // ---- bias registers: thread owns (m=m0+col, units j0+2*quad+{0,1}) ----
  float bias[2][4];
#pragma unroll
  for (int p = 0; p < 2; ++p) {
    int jl = 2 * quad + p;
#pragma unroll
    for (int gt = 0; gt < 4; ++gt) {
      int row = gt * Hx + j0 + jl;
      bias[p][gt] = b_ih[row] + b_hh[row];
    }
  }

  float cst[2] = {0.0f, 0.0f};
  float hst[2] = {0.0f, 0.0f};

  // ---- prefetch x A-frags for t=0 ----
  short8 xa[16];
  {
    const unsigned short* xrow = xT + (m0 + col) * INx + quad * 8;
#pragma unroll
    for (int kt = 0; kt < 16; ++kt) xa[kt] = *(const short8*)(xrow + kt * 32);
  }

  __syncthreads();

  int ridx = 0;                      // t % NBUF
  for (int t = 0; t < Tx; ++t) {
    int widx = ridx + 1; if (widx == NBUF) widx = 0;
    const unsigned short* hin = hbuf + (size_t)ridx * (Bx * Hx);
    unsigned short* hout = hbuf + (size_t)widx * (Bx * Hx);
    ridx = widx;

    // ---- stage this wave's 16 h rows into LDS (cached, L2-shared) ----
#pragma unroll
    for (int r = 0; r < 16; ++r) {
      const unsigned short* g = hin + (m0 + r) * Hx + ((lane ^ (r & 7)) << 3);
      short* l = hsh + (m0 + r) * Hx;
      ASYNC_CP(g, l);
      ASYNC_CP(g + 512, l + 512);
    }

    floatx4 a0a = {0.f, 0.f, 0.f, 0.f}, a0b = {0.f, 0.f, 0.f, 0.f};
    floatx4 a1a = {0.f, 0.f, 0.f, 0.f}, a1b = {0.f, 0.f, 0.f, 0.f};

    // ---- input part first (independent of h DMA): gates += x_t . W_ih^T ----
    const short* b0base = wsh + col * INx;
    const short* b1base = wsh + (col + 16) * INx;
#pragma unroll
    for (int kt = 0; kt < 16; ++kt) {
      int off = (((kt << 2) | quad) ^ swz) << 3;
      short8 b0 = *(const short8*)(b0base + off);
      short8 b1 = *(const short8*)(b1base + off);
      if (kt & 1) {
        a0b = __builtin_amdgcn_mfma_f32_16x16x32_bf16(xa[kt], b0, a0b, 0, 0, 0);
        a1b = __builtin_amdgcn_mfma_f32_16x16x32_bf16(xa[kt], b1, a1b, 0, 0, 0);
      } else {
        a0a = __builtin_amdgcn_mfma_f32_16x16x32_bf16(xa[kt], b0, a0a, 0, 0, 0);
        a1a = __builtin_amdgcn_mfma_f32_16x16x32_bf16(xa[kt], b1, a1a, 0, 0, 0);
      }
    }

    // ---- recurrent part: gates += h(t) . W_hh^T  (A from LDS, B in regs) ----
    const short* ab = hsh + (m0 + col) * Hx;
#pragma unroll
    for (int kt = 0; kt < 32; ++kt) {
      short8 af = *(const short8*)(ab + ((((kt << 2) | quad) ^ swz) << 3));
      if (kt & 1) {
        a0b = __builtin_amdgcn_mfma_f32_16x16x32_bf16(af, wf[kt][0], a0b, 0, 0, 0);
        a1b = __builtin_amdgcn_mfma_f32_16x16x32_bf16(af, wf[kt][1], a1b, 0, 0, 0);
      } else {
        a0a = __builtin_amdgcn_mfma_f32_16x16x32_bf16(af, wf[kt][0], a0a, 0, 0, 0);
        a1a = __builtin_amdgcn_mfma_f32_16x16x32_bf16(af, wf[kt][1], a1a, 0, 0, 0);
      }
    }
    floatx4 acc0 = a0a + a0b;
    floatx4 acc1 = a1a + a1b;

    // ---- transpose gates via per-wave scratch overlapped onto own h region ----
    float* gp = (float*)(hsh + wv * 16 * Hx);
#pragma unroll
    for (int i = 0; i < 4; ++i) {
      gp[(quad * 4 + i) * 33 + col] = acc0[i];
      gp[(quad * 4 + i) * 33 + 16 + col] = acc1[i];
    }

    // ---- activations: thread owns (m=m0+col, units jl=2*quad+{0,1}) ----
    unsigned int hpack = 0;
#pragma unroll
    for (int p = 0; p < 2; ++p) {
      int jl = 2 * quad + p;
      float gi = gp[col * 33 + jl] + bias[p][0];
      float gf = gp[col * 33 + 8 + jl] + bias[p][1];
      float gg = gp[col * 33 + 16 + jl] + bias[p][2];
      float go = gp[col * 33 + 24 + jl] + bias[p][3];
      float iv = sigm(gi);
      float fv = sigm(gf);
      float gv = tanh_(gg);
      float ov = sigm(go);
      float c = fv * cst[p] + iv * gv;
      cst[p] = c;
      float h = ov * tanh_(c);
      hst[p] = h;
      hpack |= ((unsigned int)f2bf(h)) << (16 * p);
    }
    // device-scope (sc1) packed store: visible at LLC once vmcnt-drained
    __hip_atomic_store(
        (unsigned int*)(hout + (m0 + col) * Hx + j0 + 2 * quad), hpack,
        __ATOMIC_RELAXED, __HIP_MEMORY_SCOPE_AGENT);

    // ---- prefetch x A-frags for t+1 (overlaps store drain) ----
    {
      int tn = (t + 1) & (Tx - 1);
      const unsigned short* xrow =
          xT + (size_t)tn * (Bx * INx) + (m0 + col) * INx + quad * 8;
#pragma unroll
      for (int kt = 0; kt < 16; ++kt) xa[kt] = *(const short8*)(xrow + kt * 32);
    }

    __syncthreads();   // drains vmcnt(0) -> all 4 waves' h stores at LLC

    // ---- signal: one release store, no RMW, no contention ----
    if (tid == 0) {
      __hip_atomic_store(&tags[bid], (unsigned)(t + 1), __ATOMIC_RELEASE,
                         __HIP_MEMORY_SCOPE_AGENT);
    }
    // ---- detect: wave 0 polls all 128 tags in one vector round ----
    if (tid < 64) {
      unsigned target = (unsigned)(t + 1);
      for (;;) {
        unsigned a = __hip_atomic_load(&tags[tid * 2], __ATOMIC_RELAXED,
                                       __HIP_MEMORY_SCOPE_AGENT);
        unsigned b = __hip_atomic_load(&tags[tid * 2 + 1], __ATOMIC_RELAXED,
                                       __HIP_MEMORY_SCOPE_AGENT);
        if (__all((a >= target) && (b >= target))) break;
        __builtin_amdgcn_s_sleep(1);
      }
    }
    __syncthreads();

    // ---- every 32 steps: acquire fence (L2 inv) so no stale line can
    //      survive to an h-buffer address reuse (distance NBUF=65) ----
    if ((t & 31) == 31) {
      __builtin_amdgcn_fence(__ATOMIC_ACQUIRE, "agent");
    }
  }

  // ---- final h -> out [B][1][H] ----
#pragma unroll
  for (int p = 0; p < 2; ++p) {
    int jl = 2 * quad + p;
    out[(m0 + col) * Hx + j0 + jl] = hst[p];
  }
}

extern "C" void kernel_launch(void* const* d_in, const int* in_sizes, int n_in,
                              void* d_out, int out_size, void* d_ws, size_t ws_size,
                              hipStream_t stream) {
  const float* input = (const float*)d_in[0];   // [B][T][IN]
  const float* W_ih  = (const float*)d_in[1];   // [4H][IN]
  const float* W_hh  = (const float*)d_in[2];   // [4H][H]
  const float* b_ih  = (const float*)d_in[3];   // [4H]
  const float* b_hh  = (const float*)d_in[4];   // [4H]
  float* out = (float*)d_out;

  char* ws = (char*)d_ws;
  unsigned int* tags = (unsigned int*)ws;                         // 512 B
  unsigned short* hbuf = (unsigned short*)(ws + 1024);            // 65 x 128 KB
  unsigned short* xT = (unsigned short*)(ws + (9u << 20));        // 32 MB @ +9 MB

  // zero tags + h buffer 0 (initial state)
  hipMemsetAsync(ws, 0, 1024 + Bx * Hx * sizeof(unsigned short), stream);

  convert_x_kernel<<<(Bx * Tx * INx) / (256 * 8), 256, 0, stream>>>(input, xT);

  lstm_persistent<<<NBLK, 256, 0, stream>>>(W_ih, W_hh, b_ih, b_hh, xT, hbuf, tags, out);
}

// Round 7
// 3270.158 us; speedup vs baseline: 1.5378x; 1.5378x over previous
//
#include <hip/hip_runtime.h>
#include <hip/hip_bf16.h>

// LSTM: B=64, T=512, IN=512, H=1024, gates i,f,g,o.
// Persistent kernel, 128 blocks x 256 threads.
// R7 = R6 minus the LDS arrival counter (busted the 160 KiB limit).
// Kept: (1) input-part MFMAs BEFORE the poll (no h dependency) to hide
// producer tail + detection; (2) x-prefetch for t+1 issued before the
// recurrent loop, off the drain path. Signal path = R4's proven
// __syncthreads (drains vmcnt) + single leaf atomicAdd from tid 0.
// Else: 65 rotating h buffers, sc1 h stores, cached global_load_lds DMA,
// acquire fence every 32 steps, W_hh in regs, W_ih bf16 in LDS, XOR
// swizzle everywhere (conflict-free, zero padding).

#define Bx 64
#define Tx 512
#define INx 512
#define Hx 1024
#define NBLK 128
#define UNITS 8
#define NBUF 65            // rotating h buffers

typedef __attribute__((ext_vector_type(8))) short short8;
typedef __attribute__((ext_vector_type(4))) float floatx4;

// normal cached direct-to-LDS copy (L2-allocating)
#define ASYNC_CP(gp, lp)                                                      \
  __builtin_amdgcn_global_load_lds(                                           \
      (const __attribute__((address_space(1))) void*)(gp),                    \
      (__attribute__((address_space(3))) void*)(lp), 16, 0, 0)

__device__ __forceinline__ unsigned short f2bf(float f) {
  unsigned u = __float_as_uint(f);
  u += 0x7FFFu + ((u >> 16) & 1u);   // round-to-nearest-even
  return (unsigned short)(u >> 16);
}
__device__ __forceinline__ float sigm(float x) { return 1.0f / (1.0f + __expf(-x)); }
__device__ __forceinline__ float tanh_(float x) { return 1.0f - 2.0f / (1.0f + __expf(2.0f * x)); }

// Convert input [B][T][IN] fp32 -> xT [T][B][IN] bf16
__global__ void convert_x_kernel(const float* __restrict__ in, unsigned short* __restrict__ xT) {
  int idx = blockIdx.x * 256 + threadIdx.x;
  int lin = idx * 8;
  int t = lin >> 15;
  int rem = lin & 32767;
  int b = rem >> 9;
  int k = rem & 511;
  const float* src = in + ((((b << 9) + t) << 9) + k);
  float4 lo = *(const float4*)src;
  float4 hi = *(const float4*)(src + 4);
  short8 o;
  o[0] = (short)f2bf(lo.x); o[1] = (short)f2bf(lo.y);
  o[2] = (short)f2bf(lo.z); o[3] = (short)f2bf(lo.w);
  o[4] = (short)f2bf(hi.x); o[5] = (short)f2bf(hi.y);
  o[6] = (short)f2bf(hi.z); o[7] = (short)f2bf(hi.w);
  *(short8*)(xT + lin) = o;
}

__global__ __launch_bounds__(256, 1) void lstm_persistent(
    const float* __restrict__ W_ih, const float* __restrict__ W_hh,
    const float* __restrict__ b_ih, const float* __restrict__ b_hh,
    const unsigned short* __restrict__ xT,   // [T][B][IN] bf16
    unsigned short* __restrict__ hbuf,       // [NBUF][B][H] bf16 (buf 0 zeroed)
    unsigned int* __restrict__ bar,          // 8 leaves, stride 32 uints (zeroed)
    float* __restrict__ out)                 // [B][H] fp32
{
  // h: 64 rows x 1024 shorts, 16B-chunk c of row m at c^(m&7)   (128 KiB)
  // wih: 32 rows x 512 shorts, chunk c of row n at c^(n&7)      (32 KiB)
  __shared__ short hsh[Bx * Hx];
  __shared__ short wsh[32 * INx];

  const int tid = threadIdx.x;
  const int lane = tid & 63;
  const int wv = tid >> 6;
  const int quad = lane >> 4;
  const int col = lane & 15;
  const int swz = col & 7;
  const int bid = blockIdx.x;
  const int j0 = bid * UNITS;
  const int m0 = wv * 16;            // batch-row base for this wave

  // ---- stage W_ih slice (fp32 -> bf16, swizzled) into LDS ----
  for (int idx = tid; idx < 32 * INx; idx += 256) {
    int n = idx >> 9;
    int k = idx & (INx - 1);
    int row = ((n >> 3) * Hx) + j0 + (n & 7);
    int c = k >> 3;
    wsh[n * INx + (((c ^ (n & 7)) << 3) | (k & 7))] = f2bf(W_ih[row * INx + k]);
  }

  // ---- preload W_hh B-fragments into registers ----
  short8 wf[32][2];
#pragma unroll
  for (int kt = 0; kt < 32; ++kt) {
#pragma unroll
    for (int nt = 0; nt < 2; ++nt) {
      int n = nt * 16 + col;
      int row = ((n >> 3) * Hx) + j0 + (n & 7);
      const float* p = W_hh + row * Hx + kt * 32 + quad * 8;
      short8 w;
#pragma unroll
      for (int j = 0; j < 8; ++j) w[j] = (short)f2bf(p[j]);
      wf[kt][nt] = w;
    }
  }

  // ---- bias registers: thread owns (m=m0+col, units j0+2*quad+{0,1}) ----
  float bias[2][4];
#pragma unroll
  for (int p = 0; p < 2; ++p) {
    int jl = 2 * quad + p;
#pragma unroll
    for (int gt = 0; gt < 4; ++gt) {
      int row = gt * Hx + j0 + jl;
      bias[p][gt] = b_ih[row] + b_hh[row];
    }
  }

  float cst[2] = {0.0f, 0.0f};
  float hst[2] = {0.0f, 0.0f};

  // ---- prefetch x A-frags for t=0 ----
  short8 xa[16];
  {
    const unsigned short* xrow = xT + (m0 + col) * INx + quad * 8;
#pragma unroll
    for (int kt = 0; kt < 16; ++kt) xa[kt] = *(const short8*)(xrow + kt * 32);
  }

  __syncthreads();

  int ridx = 0;                      // buffer holding h(t)
  for (int t = 0; t < Tx; ++t) {
    // ---- A: input part (no h dependency): gates = x_t . W_ih^T ----
    floatx4 a0a = {0.f, 0.f, 0.f, 0.f}, a0b = {0.f, 0.f, 0.f, 0.f};
    floatx4 a1a = {0.f, 0.f, 0.f, 0.f}, a1b = {0.f, 0.f, 0.f, 0.f};
    {
      const short* b0base = wsh + col * INx;
      const short* b1base = wsh + (col + 16) * INx;
#pragma unroll
      for (int kt = 0; kt < 16; ++kt) {
        int off = (((kt << 2) | quad) ^ swz) << 3;
        short8 b0 = *(const short8*)(b0base + off);
        short8 b1 = *(const short8*)(b1base + off);
        if (kt & 1) {
          a0b = __builtin_amdgcn_mfma_f32_16x16x32_bf16(xa[kt], b0, a0b, 0, 0, 0);
          a1b = __builtin_amdgcn_mfma_f32_16x16x32_bf16(xa[kt], b1, a1b, 0, 0, 0);
        } else {
          a0a = __builtin_amdgcn_mfma_f32_16x16x32_bf16(xa[kt], b0, a0a, 0, 0, 0);
          a1a = __builtin_amdgcn_mfma_f32_16x16x32_bf16(xa[kt], b1, a1a, 0, 0, 0);
        }
      }
    }

    // ---- B: wait for h(t) (all blocks' step t-1 signals) ----
    if (tid < 8) {
      unsigned target = (unsigned)t * 16u;
      while (__hip_atomic_load(&bar[tid * 32], __ATOMIC_RELAXED,
                               __HIP_MEMORY_SCOPE_AGENT) < target) {
        __builtin_amdgcn_s_sleep(1);
      }
    }
    __syncthreads();
    // every 32 steps: L2 invalidate so no stale line survives to an
    // h-buffer address reuse (reuse distance NBUF=65 > 2 fence periods)
    if ((t & 31) == 0 && t) {
      __builtin_amdgcn_fence(__ATOMIC_ACQUIRE, "agent");
    }

    // ---- D: stage this wave's 16 h rows into LDS (cached, L2-shared) ----
    int widx = ridx + 1; if (widx == NBUF) widx = 0;
    const unsigned short* hin = hbuf + (size_t)ridx * (Bx * Hx);
    unsigned short* hout = hbuf + (size_t)widx * (Bx * Hx);
    ridx = widx;
#pragma unroll
    for (int r = 0; r < 16; ++r) {
      const unsigned short* g = hin + (m0 + r) * Hx + ((lane ^ (r & 7)) << 3);
      short* l = hsh + (m0 + r) * Hx;
      ASYNC_CP(g, l);
      ASYNC_CP(g + 512, l + 512);
    }

    // ---- E: x-prefetch for t+1 (issued early; drained long before I) ----
    {
      int tn = (t + 1) & (Tx - 1);
      const unsigned short* xrow =
          xT + (size_t)tn * (Bx * INx) + (m0 + col) * INx + quad * 8;
#pragma unroll
      for (int kt = 0; kt < 16; ++kt) xa[kt] = *(const short8*)(xrow + kt * 32);
    }

    // ---- F: recurrent part: gates += h(t) . W_hh^T ----
    const short* ab = hsh + (m0 + col) * Hx;
#pragma unroll
    for (int kt = 0; kt < 32; ++kt) {
      short8 af = *(const short8*)(ab + ((((kt << 2) | quad) ^ swz) << 3));
      if (kt & 1) {
        a0b = __builtin_amdgcn_mfma_f32_16x16x32_bf16(af, wf[kt][0], a0b, 0, 0, 0);
        a1b = __builtin_amdgcn_mfma_f32_16x16x32_bf16(af, wf[kt][1], a1b, 0, 0, 0);
      } else {
        a0a = __builtin_amdgcn_mfma_f32_16x16x32_bf16(af, wf[kt][0], a0a, 0, 0, 0);
        a1a = __builtin_amdgcn_mfma_f32_16x16x32_bf16(af, wf[kt][1], a1a, 0, 0, 0);
      }
    }
    floatx4 acc0 = a0a + a0b;
    floatx4 acc1 = a1a + a1b;

    // ---- G: transpose gates via per-wave scratch on own h region ----
    float* gp = (float*)(hsh + wv * 16 * Hx);
#pragma unroll
    for (int i = 0; i < 4; ++i) {
      gp[(quad * 4 + i) * 33 + col] = acc0[i];
      gp[(quad * 4 + i) * 33 + 16 + col] = acc1[i];
    }

    // ---- H: activations; thread owns (m=m0+col, units jl=2*quad+{0,1}) ----
    unsigned int hpack = 0;
#pragma unroll
    for (int p = 0; p < 2; ++p) {
      int jl = 2 * quad + p;
      float gi = gp[col * 33 + jl] + bias[p][0];
      float gf = gp[col * 33 + 8 + jl] + bias[p][1];
      float gg = gp[col * 33 + 16 + jl] + bias[p][2];
      float go = gp[col * 33 + 24 + jl] + bias[p][3];
      float iv = sigm(gi);
      float fv = sigm(gf);
      float gv = tanh_(gg);
      float ov = sigm(go);
      float c = fv * cst[p] + iv * gv;
      cst[p] = c;
      float h = ov * tanh_(c);
      hst[p] = h;
      hpack |= ((unsigned int)f2bf(h)) << (16 * p);
    }
    // device-scope (sc1) packed store: write-through to LLC
    __hip_atomic_store(
        (unsigned int*)(hout + (m0 + col) * Hx + j0 + 2 * quad), hpack,
        __ATOMIC_RELAXED, __HIP_MEMORY_SCOPE_AGENT);

    // ---- I: drain (s_barrier implies vmcnt(0) wait) + one leaf signal ----
    __syncthreads();
    if (tid == 0) {
      __hip_atomic_fetch_add(&bar[(bid & 7) * 32], 1u, __ATOMIC_RELAXED,
                             __HIP_MEMORY_SCOPE_AGENT);
    }
  }

  // ---- final h -> out [B][1][H] ----
#pragma unroll
  for (int p = 0; p < 2; ++p) {
    int jl = 2 * quad + p;
    out[(m0 + col) * Hx + j0 + jl] = hst[p];
  }
}

extern "C" void kernel_launch(void* const* d_in, const int* in_sizes, int n_in,
                              void* d_out, int out_size, void* d_ws, size_t ws_size,
                              hipStream_t stream) {
  const float* input = (const float*)d_in[0];   // [B][T][IN]
  const float* W_ih  = (const float*)d_in[1];   // [4H][IN]
  const float* W_hh  = (const float*)d_in[2];   // [4H][H]
  const float* b_ih  = (const float*)d_in[3];   // [4H]
  const float* b_hh  = (const float*)d_in[4];   // [4H]
  float* out = (float*)d_out;

  char* ws = (char*)d_ws;
  unsigned int* bar = (unsigned int*)ws;                          // 1 KB
  unsigned short* hbuf = (unsigned short*)(ws + 1024);            // 65 x 128 KB
  unsigned short* xT = (unsigned short*)(ws + (9u << 20));        // 32 MB @ +9 MB

  // zero leaves + h buffer 0 (initial state)
  hipMemsetAsync(ws, 0, 1024 + Bx * Hx * sizeof(unsigned short), stream);

  convert_x_kernel<<<(Bx * Tx * INx) / (256 * 8), 256, 0, stream>>>(input, xT);

  lstm_persistent<<<NBLK, 256, 0, stream>>>(W_ih, W_hh, b_ih, b_hh, xT, hbuf, bar, out);
}

// Round 8
// 2832.315 us; speedup vs baseline: 1.7756x; 1.1546x over previous
//
#include <hip/hip_runtime.h>
#include <hip/hip_bf16.h>

// LSTM: B=64, T=512, IN=512, H=1024, gates i,f,g,o.
// Persistent kernel, 128 blocks x 256 threads.
// R8: WAVE-SPECIALIZED CHAINS. Batch recurrence is diagonal (h[b] depends
// only on h[b]), and each wave already owns 16 batch rows end-to-end. So
// the grid barrier splits into 4 independent per-wave-index sync domains
// (each an R4-proven 8-leaf x 16-writer atomic tree with 8-lane poll).
// NO __syncthreads in the loop: no intra-block rendezvous, no
// max-over-waves jitter coupling; per-wave vmcnt drains only own stores.
// Hazard control (explicit, since no barriers): compiler barrier after
// poll; s_waitcnt vmcnt(0) between DMA issue and hsh ds_reads;
// vmcnt(0)+lgkmcnt(0) before leaf signal.
// Else: 65 rotating h buffers, sc1 h stores, cached global_load_lds DMA,
// acquire fence every 32 steps (per wave), W_hh in regs, W_ih bf16 in LDS,
// XOR swizzle everywhere (conflict-free, zero padding).

#define Bx 64
#define Tx 512
#define INx 512
#define Hx 1024
#define NBLK 128
#define UNITS 8
#define NBUF 65            // rotating h buffers

typedef __attribute__((ext_vector_type(8))) short short8;
typedef __attribute__((ext_vector_type(4))) float floatx4;

// normal cached direct-to-LDS copy (L2-allocating)
#define ASYNC_CP(gp, lp)                                                      \
  __builtin_amdgcn_global_load_lds(                                           \
      (const __attribute__((address_space(1))) void*)(gp),                    \
      (__attribute__((address_space(3))) void*)(lp), 16, 0, 0)

__device__ __forceinline__ unsigned short f2bf(float f) {
  unsigned u = __float_as_uint(f);
  u += 0x7FFFu + ((u >> 16) & 1u);   // round-to-nearest-even
  return (unsigned short)(u >> 16);
}
__device__ __forceinline__ float sigm(float x) { return 1.0f / (1.0f + __expf(-x)); }
__device__ __forceinline__ float tanh_(float x) { return 1.0f - 2.0f / (1.0f + __expf(2.0f * x)); }

// Convert input [B][T][IN] fp32 -> xT [T][B][IN] bf16
__global__ void convert_x_kernel(const float* __restrict__ in, unsigned short* __restrict__ xT) {
  int idx = blockIdx.x * 256 + threadIdx.x;
  int lin = idx * 8;
  int t = lin >> 15;
  int rem = lin & 32767;
  int b = rem >> 9;
  int k = rem & 511;
  const float* src = in + ((((b << 9) + t) << 9) + k);
  float4 lo = *(const float4*)src;
  float4 hi = *(const float4*)(src + 4);
  short8 o;
  o[0] = (short)f2bf(lo.x); o[1] = (short)f2bf(lo.y);
  o[2] = (short)f2bf(lo.z); o[3] = (short)f2bf(lo.w);
  o[4] = (short)f2bf(hi.x); o[5] = (short)f2bf(hi.y);
  o[6] = (short)f2bf(hi.z); o[7] = (short)f2bf(hi.w);
  *(short8*)(xT + lin) = o;
}

__global__ __launch_bounds__(256, 1) void lstm_persistent(
    const float* __restrict__ W_ih, const float* __restrict__ W_hh,
    const float* __restrict__ b_ih, const float* __restrict__ b_hh,
    const unsigned short* __restrict__ xT,   // [T][B][IN] bf16
    unsigned short* __restrict__ hbuf,       // [NBUF][B][H] bf16 (buf 0 zeroed)
    unsigned int* __restrict__ bar,          // 4 chains x 8 leaves x 32 uints
    float* __restrict__ out)                 // [B][H] fp32
{
  // h: 64 rows x 1024 shorts, 16B-chunk c of row m at c^(m&7)   (128 KiB)
  // wih: 32 rows x 512 shorts, chunk c of row n at c^(n&7)      (32 KiB)
  __shared__ short hsh[Bx * Hx];
  __shared__ short wsh[32 * INx];

  const int tid = threadIdx.x;
  const int lane = tid & 63;
  const int wv = tid >> 6;
  const int quad = lane >> 4;
  const int col = lane & 15;
  const int swz = col & 7;
  const int bid = blockIdx.x;
  const int j0 = bid * UNITS;
  const int m0 = wv * 16;            // batch-row base for this wave (wave-owned)

  unsigned int* leaf = bar + wv * 256;   // this chain's 8 leaves (128B stride)

  // ---- stage W_ih slice (fp32 -> bf16, swizzled) into LDS ----
  for (int idx = tid; idx < 32 * INx; idx += 256) {
    int n = idx >> 9;
    int k = idx & (INx - 1);
    int row = ((n >> 3) * Hx) + j0 + (n & 7);
    int c = k >> 3;
    wsh[n * INx + (((c ^ (n & 7)) << 3) | (k & 7))] = f2bf(W_ih[row * INx + k]);
  }

  // ---- preload W_hh B-fragments into registers ----
  short8 wf[32][2];
#pragma unroll
  for (int kt = 0; kt < 32; ++kt) {
#pragma unroll
    for (int nt = 0; nt < 2; ++nt) {
      int n = nt * 16 + col;
      int row = ((n >> 3) * Hx) + j0 + (n & 7);
      const float* p = W_hh + row * Hx + kt * 32 + quad * 8;
      short8 w;
#pragma unroll
      for (int j = 0; j < 8; ++j) w[j] = (short)f2bf(p[j]);
      wf[kt][nt] = w;
    }
  }

  // ---- bias registers: thread owns (m=m0+col, units j0+2*quad+{0,1}) ----
  float bias[2][4];
#pragma unroll
  for (int p = 0; p < 2; ++p) {
    int jl = 2 * quad + p;
#pragma unroll
    for (int gt = 0; gt < 4; ++gt) {
      int row = gt * Hx + j0 + jl;
      bias[p][gt] = b_ih[row] + b_hh[row];
    }
  }

  float cst[2] = {0.0f, 0.0f};
  float hst[2] = {0.0f, 0.0f};

  // ---- prefetch x A-frags for t=0 ----
  short8 xa[16];
  {
    const unsigned short* xrow = xT + (m0 + col) * INx + quad * 8;
#pragma unroll
    for (int kt = 0; kt < 16; ++kt) xa[kt] = *(const short8*)(xrow + kt * 32);
  }

  __syncthreads();   // wsh staging complete (only pre-loop barrier)

  int ridx = 0;                      // buffer holding h(t)
  for (int t = 0; t < Tx; ++t) {
    // ---- A: input part (no h dependency): gates = x_t . W_ih^T ----
    floatx4 a0a = {0.f, 0.f, 0.f, 0.f}, a0b = {0.f, 0.f, 0.f, 0.f};
    floatx4 a1a = {0.f, 0.f, 0.f, 0.f}, a1b = {0.f, 0.f, 0.f, 0.f};
    {
      const short* b0base = wsh + col * INx;
      const short* b1base = wsh + (col + 16) * INx;
#pragma unroll
      for (int kt = 0; kt < 16; ++kt) {
        int off = (((kt << 2) | quad) ^ swz) << 3;
        short8 b0 = *(const short8*)(b0base + off);
        short8 b1 = *(const short8*)(b1base + off);
        if (kt & 1) {
          a0b = __builtin_amdgcn_mfma_f32_16x16x32_bf16(xa[kt], b0, a0b, 0, 0, 0);
          a1b = __builtin_amdgcn_mfma_f32_16x16x32_bf16(xa[kt], b1, a1b, 0, 0, 0);
        } else {
          a0a = __builtin_amdgcn_mfma_f32_16x16x32_bf16(xa[kt], b0, a0a, 0, 0, 0);
          a1a = __builtin_amdgcn_mfma_f32_16x16x32_bf16(xa[kt], b1, a1a, 0, 0, 0);
        }
      }
    }

    // ---- B: wait for this chain's h(t): all 128 blocks' wave wv ----
    {
      unsigned target = (unsigned)t * 16u;
      for (;;) {
        unsigned v = target;
        if (lane < 8)
          v = __hip_atomic_load(&leaf[lane * 32], __ATOMIC_RELAXED,
                                __HIP_MEMORY_SCOPE_AGENT);
        if (__all(v >= target)) break;
        __builtin_amdgcn_s_sleep(1);
      }
    }
    asm volatile("" ::: "memory");   // no DMA hoisting above the spin

    // every 32 steps: L2 invalidate so no stale line survives to an
    // h-buffer address reuse (reuse distance NBUF=65 > 2 fence periods)
    if ((t & 31) == 0 && t) {
      __builtin_amdgcn_fence(__ATOMIC_ACQUIRE, "agent");
    }

    // ---- D: stage this wave's 16 h rows into LDS (cached, L2-shared) ----
    int widx = ridx + 1; if (widx == NBUF) widx = 0;
    const unsigned short* hin = hbuf + (size_t)ridx * (Bx * Hx);
    unsigned short* hout = hbuf + (size_t)widx * (Bx * Hx);
    ridx = widx;
#pragma unroll
    for (int r = 0; r < 16; ++r) {
      const unsigned short* g = hin + (m0 + r) * Hx + ((lane ^ (r & 7)) << 3);
      short* l = hsh + (m0 + r) * Hx;
      ASYNC_CP(g, l);
      ASYNC_CP(g + 512, l + 512);
    }

    // ---- E: x-prefetch for t+1 (overlaps DMA fill) ----
    {
      int tn = (t + 1) & (Tx - 1);
      const unsigned short* xrow =
          xT + (size_t)tn * (Bx * INx) + (m0 + col) * INx + quad * 8;
#pragma unroll
      for (int kt = 0; kt < 16; ++kt) xa[kt] = *(const short8*)(xrow + kt * 32);
    }

    // DMA landed before reading hsh (also drains x-prefetch; both ~1 RT)
    asm volatile("s_waitcnt vmcnt(0)" ::: "memory");

    // ---- F: recurrent part: gates += h(t) . W_hh^T ----
    const short* ab = hsh + (m0 + col) * Hx;
#pragma unroll
    for (int kt = 0; kt < 32; ++kt) {
      short8 af = *(const short8*)(ab + ((((kt << 2) | quad) ^ swz) << 3));
      if (kt & 1) {
        a0b = __builtin_amdgcn_mfma_f32_16x16x32_bf16(af, wf[kt][0], a0b, 0, 0, 0);
        a1b = __builtin_amdgcn_mfma_f32_16x16x32_bf16(af, wf[kt][1], a1b, 0, 0, 0);
      } else {
        a0a = __builtin_amdgcn_mfma_f32_16x16x32_bf16(af, wf[kt][0], a0a, 0, 0, 0);
        a1a = __builtin_amdgcn_mfma_f32_16x16x32_bf16(af, wf[kt][1], a1a, 0, 0, 0);
      }
    }
    floatx4 acc0 = a0a + a0b;
    floatx4 acc1 = a1a + a1b;

    // ---- G: transpose gates via per-wave scratch on own h region ----
    float* gp = (float*)(hsh + wv * 16 * Hx);
#pragma unroll
    for (int i = 0; i < 4; ++i) {
      gp[(quad * 4 + i) * 33 + col] = acc0[i];
      gp[(quad * 4 + i) * 33 + 16 + col] = acc1[i];
    }

    // ---- H: activations; thread owns (m=m0+col, units jl=2*quad+{0,1}) ----
    unsigned int hpack = 0;
#pragma unroll
    for (int p = 0; p < 2; ++p) {
      int jl = 2 * quad + p;
      float gi = gp[col * 33 + jl] + bias[p][0];
      float gf = gp[col * 33 + 8 + jl] + bias[p][1];
      float gg = gp[col * 33 + 16 + jl] + bias[p][2];
      float go = gp[col * 33 + 24 + jl] + bias[p][3];
      float iv = sigm(gi);
      float fv = sigm(gf);
      float gv = tanh_(gg);
      float ov = sigm(go);
      float c = fv * cst[p] + iv * gv;
      cst[p] = c;
      float h = ov * tanh_(c);
      hst[p] = h;
      hpack |= ((unsigned int)f2bf(h)) << (16 * p);
    }
    // device-scope (sc1) packed store: write-through to LLC
    __hip_atomic_store(
        (unsigned int*)(hout + (m0 + col) * Hx + j0 + 2 * quad), hpack,
        __ATOMIC_RELAXED, __HIP_MEMORY_SCOPE_AGENT);

    // ---- I: per-wave drain + leaf signal (no block rendezvous) ----
    // vmcnt(0): h stores at LLC; lgkmcnt(0): gp scratch reads done (closes
    // WAR against next iteration's DMA into the same LDS region).
    asm volatile("s_waitcnt vmcnt(0) lgkmcnt(0)" ::: "memory");
    if (lane == 0) {
      __hip_atomic_fetch_add(&leaf[(bid & 7) * 32], 1u, __ATOMIC_RELAXED,
                             __HIP_MEMORY_SCOPE_AGENT);
    }
  }

  // ---- final h -> out [B][1][H] ----
#pragma unroll
  for (int p = 0; p < 2; ++p) {
    int jl = 2 * quad + p;
    out[(m0 + col) * Hx + j0 + jl] = hst[p];
  }
}

extern "C" void kernel_launch(void* const* d_in, const int* in_sizes, int n_in,
                              void* d_out, int out_size, void* d_ws, size_t ws_size,
                              hipStream_t stream) {
  const float* input = (const float*)d_in[0];   // [B][T][IN]
  const float* W_ih  = (const float*)d_in[1];   // [4H][IN]
  const float* W_hh  = (const float*)d_in[2];   // [4H][H]
  const float* b_ih  = (const float*)d_in[3];   // [4H]
  const float* b_hh  = (const float*)d_in[4];   // [4H]
  float* out = (float*)d_out;

  char* ws = (char*)d_ws;
  unsigned int* bar = (unsigned int*)ws;                          // 4 KB
  unsigned short* hbuf = (unsigned short*)(ws + 8192);            // 65 x 128 KB
  unsigned short* xT = (unsigned short*)(ws + (9u << 20));        // 32 MB @ +9 MB

  // zero 4 chains' leaves + h buffer 0 (initial state)
  hipMemsetAsync(ws, 0, 8192 + Bx * Hx * sizeof(unsigned short), stream);

  convert_x_kernel<<<(Bx * Tx * INx) / (256 * 8), 256, 0, stream>>>(input, xT);

  lstm_persistent<<<NBLK, 256, 0, stream>>>(W_ih, W_hh, b_ih, b_hh, xT, hbuf, bar, out);
}